// Round 1
// baseline (527.079 us; speedup 1.0000x reference)
//
#include <hip/hip_runtime.h>

#define NN 2048
#define NN2 (NN * NN)

__device__ __forceinline__ float ldz(const float* __restrict__ a, int i, int j) {
    // zero (Dirichlet) halo
    if ((unsigned)i >= (unsigned)NN || (unsigned)j >= (unsigned)NN) return 0.f;
    return a[i * NN + j];
}
__device__ __forceinline__ float lde(const float* __restrict__ a, int i, int j) {
    // edge-replicate halo
    i = i < 0 ? 0 : (i > NN - 1 ? NN - 1 : i);
    j = j < 0 ? 0 : (j > NN - 1 ? NN - 1 : j);
    return a[i * NN + j];
}

// ---------------- Petrov-Galerkin k coefficient (used for (u,v) and (b_u,b_v)) -------------
__global__ __launch_bounds__(256) void k_pg1(const float* __restrict__ u, const float* __restrict__ v,
                                             const float* __restrict__ k1,
                                             float* __restrict__ ku, float* __restrict__ kv) {
    int j = blockIdx.x * blockDim.x + threadIdx.x;
    int i = blockIdx.y * blockDim.y + threadIdx.y;
    int idx = i * NN + j;
    float uc = u[idx], vc = v[idx];
    float ul = ldz(u, i, j - 1), ur = ldz(u, i, j + 1), ut = ldz(u, i - 1, j), ub = ldz(u, i + 1, j);
    float vl = ldz(v, i, j - 1), vr = ldz(v, i, j + 1), vt = ldz(v, i - 1, j), vb = ldz(v, i + 1, j);
    float ADxu = 0.5f * (ur - ul), ADyu = 0.5f * (ub - ut);
    float ADxv = 0.5f * (vr - vl), ADyv = 0.5f * (vb - vt);
    float Lu = ul + ur + ut + ub - 4.f * uc;
    float Lv = vl + vr + vt + vb - 4.f * vc;
    float s = fabsf(uc) + fabsf(vc);
    float kuv = 0.25f * fabsf(0.5f * s * Lu) / (0.001f + 0.5f * (fabsf(ADxu) + fabsf(ADyu)));
    float kvv = 0.25f * fabsf(0.5f * s * Lv) / (0.001f + 0.5f * (fabsf(ADxv) + fabsf(ADyv)));
    float k1c = k1[idx];
    ku[idx] = fminf(kuv, k1c);
    kv[idx] = fminf(kvv, k1c);
}

// ---------------- predictor: b_u, b_v ----------------
__global__ __launch_bounds__(256) void k_pred(const float* __restrict__ u, const float* __restrict__ v,
                                              const float* __restrict__ p,
                                              const float* __restrict__ ku, const float* __restrict__ kv,
                                              float* __restrict__ bu, float* __restrict__ bv) {
    const float DT = 0.01f;
    int j = blockIdx.x * blockDim.x + threadIdx.x;
    int i = blockIdx.y * blockDim.y + threadIdx.y;
    int idx = i * NN + j;
    float uc = u[idx], vc = v[idx];
    float ul = ldz(u, i, j - 1), ur = ldz(u, i, j + 1), ut = ldz(u, i - 1, j), ub = ldz(u, i + 1, j);
    float vl = ldz(v, i, j - 1), vr = ldz(v, i, j + 1), vt = ldz(v, i - 1, j), vb = ldz(v, i + 1, j);
    float kuc = ku[idx], kvc = kv[idx];
    float kul = ldz(ku, i, j - 1), kur = ldz(ku, i, j + 1), kut = ldz(ku, i - 1, j), kub = ldz(ku, i + 1, j);
    float kvl = ldz(kv, i, j - 1), kvr = ldz(kv, i, j + 1), kvt = ldz(kv, i - 1, j), kvb = ldz(kv, i + 1, j);
    float ADxu = 0.5f * (ur - ul), ADyu = 0.5f * (ub - ut);
    float ADxv = 0.5f * (vr - vl), ADyv = 0.5f * (vb - vt);
    float Lu = ul + ur + ut + ub - 4.f * uc;
    float Lv = vl + vr + vt + vb - 4.f * vc;
    float Lku = kul + kur + kut + kub - 4.f * kuc;
    float Lkv = kvl + kvr + kvt + kvb - 4.f * kvc;
    float Luku = ul * kul + ur * kur + ut * kut + ub * kub - 4.f * uc * kuc;
    float Lvkv = vl * kvl + vr * kvr + vt * kvt + vb * kvb - 4.f * vc * kvc;
    float kx = 1.5f * (kuc * Lu + Luku - uc * Lku);
    float ky = 1.5f * (kvc * Lv + Lvkv - vc * Lkv);
    float Grapx = 0.5f * (lde(p, i, j + 1) - lde(p, i, j - 1)) * DT;
    float Grapy = 0.5f * (lde(p, i + 1, j) - lde(p, i - 1, j)) * DT;
    bu[idx] = uc + 0.5f * (kx * DT - uc * ADxu * DT - vc * ADyu * DT) - Grapx;
    bv[idx] = vc + 0.5f * (ky * DT - uc * ADxv * DT - vc * ADyv * DT) - Grapy;
}

// ---------------- corrector: u_new, v_new ----------------
__global__ __launch_bounds__(256) void k_corr(const float* __restrict__ u, const float* __restrict__ v,
                                              const float* __restrict__ p,
                                              const float* __restrict__ bu, const float* __restrict__ bv,
                                              const float* __restrict__ ku, const float* __restrict__ kv,
                                              const float* __restrict__ Fx, const float* __restrict__ Fy,
                                              float* __restrict__ un, float* __restrict__ vn) {
    const float DT = 0.01f;
    int j = blockIdx.x * blockDim.x + threadIdx.x;
    int i = blockIdx.y * blockDim.y + threadIdx.y;
    int idx = i * NN + j;
    float uc = u[idx], vc = v[idx];
    float buc = bu[idx], bvc = bv[idx];
    float bul = ldz(bu, i, j - 1), bur = ldz(bu, i, j + 1), but = ldz(bu, i - 1, j), bub = ldz(bu, i + 1, j);
    float bvl = ldz(bv, i, j - 1), bvr = ldz(bv, i, j + 1), bvt = ldz(bv, i - 1, j), bvb = ldz(bv, i + 1, j);
    float kuc = ku[idx], kvc = kv[idx];
    float kul = ldz(ku, i, j - 1), kur = ldz(ku, i, j + 1), kut = ldz(ku, i - 1, j), kub = ldz(ku, i + 1, j);
    float kvl = ldz(kv, i, j - 1), kvr = ldz(kv, i, j + 1), kvt = ldz(kv, i - 1, j), kvb = ldz(kv, i + 1, j);
    float ul = ldz(u, i, j - 1), ur = ldz(u, i, j + 1), ut = ldz(u, i - 1, j), ub = ldz(u, i + 1, j);
    float vl = ldz(v, i, j - 1), vr = ldz(v, i, j + 1), vt = ldz(v, i - 1, j), vb = ldz(v, i + 1, j);
    float ADxbu = 0.5f * (bur - bul), ADybu = 0.5f * (bub - but);
    float ADxbv = 0.5f * (bvr - bvl), ADybv = 0.5f * (bvb - bvt);
    float Lbu = bul + bur + but + bub - 4.f * buc;
    float Lbv = bvl + bvr + bvt + bvb - 4.f * bvc;
    float Lku = kul + kur + kut + kub - 4.f * kuc;
    float Lkv = kvl + kvr + kvt + kvb - 4.f * kvc;
    // product uses the ORIGINAL velocities (torch closes over global values_uu/vv)
    float Luku = ul * kul + ur * kur + ut * kut + ub * kub - 4.f * uc * kuc;
    float Lvkv = vl * kvl + vr * kvr + vt * kvt + vb * kvb - 4.f * vc * kvc;
    float kx = 1.5f * (kuc * Lbu + Luku - buc * Lku);
    float ky = 1.5f * (kvc * Lbv + Lvkv - bvc * Lkv);
    float Grapx = 0.5f * (lde(p, i, j + 1) - lde(p, i, j - 1)) * DT;
    float Grapy = 0.5f * (lde(p, i + 1, j) - lde(p, i - 1, j)) * DT;
    un[idx] = uc + kx * DT - buc * ADxbu * DT - bvc * ADybu * DT - Grapx - Fx[idx] * DT;
    vn[idx] = vc + ky * DT - buc * ADxbv * DT - bvc * ADybv * DT - Grapy - Fy[idx] * DT;
}

// ---------------- pressure RHS: b = -div(u_new)/DT ----------------
__global__ __launch_bounds__(256) void k_rhs(const float* __restrict__ un, const float* __restrict__ vn,
                                             float* __restrict__ b) {
    const float INVDT = 100.0f;
    int j = blockIdx.x * blockDim.x + threadIdx.x;
    int i = blockIdx.y * blockDim.y + threadIdx.y;
    int idx = i * NN + j;
    float adx = 0.5f * (ldz(un, i, j + 1) - ldz(un, i, j - 1));
    float ady = 0.5f * (ldz(vn, i + 1, j) - ldz(vn, i - 1, j));
    b[idx] = -(adx + ady) * INVDT;
}

// ---------------- residual r = Lap_edge(p) - b ----------------
__global__ __launch_bounds__(256) void k_res(const float* __restrict__ p, const float* __restrict__ b,
                                             float* __restrict__ r) {
    int j = blockIdx.x * blockDim.x + threadIdx.x;
    int i = blockIdx.y * blockDim.y + threadIdx.y;
    int idx = i * NN + j;
    float pc = p[idx];
    float nb = lde(p, i - 1, j) + lde(p, i + 1, j) + lde(p, i, j - 1) + lde(p, i, j + 1);
    r[idx] = (nb - 4.f * pc) - b[idx];
}

// ---------------- fused 2-level restriction ----------------
__global__ __launch_bounds__(256) void k_restrict2(const float* __restrict__ src,
                                                   float* __restrict__ dst1, float* __restrict__ dst2,
                                                   int n_src) {
    int j = blockIdx.x * blockDim.x + threadIdx.x;
    int i = blockIdx.y * blockDim.y + threadIdx.y;
    int n4 = n_src >> 2;
    int n2 = n_src >> 1;
    const float4* r0 = reinterpret_cast<const float4*>(src + (4 * i + 0) * n_src + 4 * j);
    const float4* r1 = reinterpret_cast<const float4*>(src + (4 * i + 1) * n_src + 4 * j);
    const float4* r2 = reinterpret_cast<const float4*>(src + (4 * i + 2) * n_src + 4 * j);
    const float4* r3 = reinterpret_cast<const float4*>(src + (4 * i + 3) * n_src + 4 * j);
    float4 a0 = *r0, a1 = *r1, a2 = *r2, a3 = *r3;
    float s00 = a0.x + a0.y + a1.x + a1.y;
    float s01 = a0.z + a0.w + a1.z + a1.w;
    float s10 = a2.x + a2.y + a3.x + a3.y;
    float s11 = a2.z + a2.w + a3.z + a3.w;
    *reinterpret_cast<float2*>(dst1 + (2 * i) * n2 + 2 * j)     = make_float2(0.25f * s00, 0.25f * s01);
    *reinterpret_cast<float2*>(dst1 + (2 * i + 1) * n2 + 2 * j) = make_float2(0.25f * s10, 0.25f * s11);
    dst2[i * n4 + j] = 0.0625f * (s00 + s01 + s10 + s11);
}

// ---------------- all coarse levels (<=128) in one block ----------------
__global__ __launch_bounds__(1024) void k_small(const float* __restrict__ r128,
                                                float* __restrict__ w128_out,
                                                float* __restrict__ r2_out) {
    __shared__ float sr64[64 * 64];
    __shared__ float sr32[32 * 32];
    __shared__ float sr16[16 * 16];
    __shared__ float sr8[8 * 8];
    __shared__ float sr4[16];
    __shared__ float sr2[4];
    __shared__ float wa[64 * 64];
    __shared__ float wb[64 * 64];
    int t = threadIdx.x;

    // restrict 128 -> 64
    for (int idx = t; idx < 64 * 64; idx += 1024) {
        int i = idx >> 6, j = idx & 63;
        const float* s0 = r128 + (2 * i) * 128 + 2 * j;
        sr64[idx] = 0.25f * (s0[0] + s0[1] + s0[128] + s0[129]);
    }
    __syncthreads();
    // 64 -> 32
    if (t < 32 * 32) {
        int i = t >> 5, j = t & 31;
        const float* s0 = sr64 + (2 * i) * 64 + 2 * j;
        sr32[t] = 0.25f * (s0[0] + s0[1] + s0[64] + s0[65]);
    }
    __syncthreads();
    if (t < 16 * 16) {
        int i = t >> 4, j = t & 15;
        const float* s0 = sr32 + (2 * i) * 32 + 2 * j;
        sr16[t] = 0.25f * (s0[0] + s0[1] + s0[32] + s0[33]);
    }
    __syncthreads();
    if (t < 64) {
        int i = t >> 3, j = t & 7;
        const float* s0 = sr16 + (2 * i) * 16 + 2 * j;
        sr8[t] = 0.25f * (s0[0] + s0[1] + s0[16] + s0[17]);
    }
    __syncthreads();
    if (t < 16) {
        int i = t >> 2, j = t & 3;
        const float* s0 = sr8 + (2 * i) * 8 + 2 * j;
        sr4[t] = 0.25f * (s0[0] + s0[1] + s0[8] + s0[9]);
    }
    __syncthreads();
    if (t < 4) {
        int i = t >> 1, j = t & 1;
        const float* s0 = sr4 + (2 * i) * 4 + 2 * j;
        sr2[t] = 0.25f * (s0[0] + s0[1] + s0[4] + s0[5]);
        r2_out[t] = sr2[t];  // final returned r (2x2)
        // prolongation start: w = 0 at 2x2 -> smoothed w = -r2/4, upsample into wa (4x4)
        float ws = -0.25f * sr2[t];
        wa[(2 * i) * 4 + 2 * j] = ws;
        wa[(2 * i) * 4 + 2 * j + 1] = ws;
        wa[(2 * i + 1) * 4 + 2 * j] = ws;
        wa[(2 * i + 1) * 4 + 2 * j + 1] = ws;
    }
    __syncthreads();

    // generic smooth (zero-pad Jacobi, w_new=(nbrsum-r)/4) + 2x upsample
    auto step = [&](const float* win, const float* rl, float* wout, int s) {
        for (int idx = t; idx < s * s; idx += 1024) {
            int i = idx / s, j = idx - i * s;
            float up = i > 0 ? win[(i - 1) * s + j] : 0.f;
            float dn = i < s - 1 ? win[(i + 1) * s + j] : 0.f;
            float lf = j > 0 ? win[i * s + j - 1] : 0.f;
            float rt = j < s - 1 ? win[i * s + j + 1] : 0.f;
            float ws = 0.25f * (up + dn + lf + rt - rl[idx]);
            int o = 2 * s;
            wout[(2 * i) * o + 2 * j] = ws;
            wout[(2 * i) * o + 2 * j + 1] = ws;
            wout[(2 * i + 1) * o + 2 * j] = ws;
            wout[(2 * i + 1) * o + 2 * j + 1] = ws;
        }
    };
    step(wa, sr4, wb, 4);
    __syncthreads();
    step(wb, sr8, wa, 8);
    __syncthreads();
    step(wa, sr16, wb, 16);
    __syncthreads();
    step(wb, sr32, wa, 32);
    __syncthreads();
    step(wa, sr64, w128_out, 64);  // final write to global (128x128)
}

// ---------------- smooth + upsample, one level ----------------
__global__ __launch_bounds__(256) void k_prolong(const float* __restrict__ win, const float* __restrict__ rl,
                                                 float* __restrict__ wout, int n) {
    int j = blockIdx.x * blockDim.x + threadIdx.x;
    int i = blockIdx.y * blockDim.y + threadIdx.y;
    float up = i > 0 ? win[(i - 1) * n + j] : 0.f;
    float dn = i < n - 1 ? win[(i + 1) * n + j] : 0.f;
    float lf = j > 0 ? win[i * n + j - 1] : 0.f;
    float rt = j < n - 1 ? win[i * n + j + 1] : 0.f;
    float ws = 0.25f * (up + dn + lf + rt - rl[i * n + j]);
    int o = 2 * n;
    float2 vv = make_float2(ws, ws);
    *reinterpret_cast<float2*>(wout + (2 * i) * o + 2 * j) = vv;
    *reinterpret_cast<float2*>(wout + (2 * i + 1) * o + 2 * j) = vv;
}

// ---------------- p update: p_new = (nbrsum_edge(p - w) - b)/4 ----------------
__device__ __forceinline__ float tpw(const float* __restrict__ p, const float* __restrict__ w, int i, int j) {
    i = i < 0 ? 0 : (i > NN - 1 ? NN - 1 : i);
    j = j < 0 ? 0 : (j > NN - 1 ? NN - 1 : j);
    int idx = i * NN + j;
    return p[idx] - w[idx];
}
__global__ __launch_bounds__(256) void k_pupd(const float* __restrict__ p, const float* __restrict__ w,
                                              const float* __restrict__ b, float* __restrict__ pdst) {
    int j = blockIdx.x * blockDim.x + threadIdx.x;
    int i = blockIdx.y * blockDim.y + threadIdx.y;
    int idx = i * NN + j;
    float nb = tpw(p, w, i - 1, j) + tpw(p, w, i + 1, j) + tpw(p, w, i, j - 1) + tpw(p, w, i, j + 1);
    pdst[idx] = 0.25f * (nb - b[idx]);
}

// ---------------- final projection (pointwise in u/v, in-place safe) ----------------
__global__ __launch_bounds__(256) void k_fcorr(const float* __restrict__ p,
                                               float* __restrict__ un, float* __restrict__ vn) {
    const float DT = 0.01f;
    int j = blockIdx.x * blockDim.x + threadIdx.x;
    int i = blockIdx.y * blockDim.y + threadIdx.y;
    int idx = i * NN + j;
    float gx = 0.5f * (lde(p, i, j + 1) - lde(p, i, j - 1)) * DT;
    float gy = 0.5f * (lde(p, i + 1, j) - lde(p, i - 1, j)) * DT;
    un[idx] -= gx;
    vn[idx] -= gy;
}

extern "C" void kernel_launch(void* const* d_in, const int* in_sizes, int n_in,
                              void* d_out, int out_size, void* d_ws, size_t ws_size,
                              hipStream_t stream) {
    const float* u  = (const float*)d_in[0];
    const float* v  = (const float*)d_in[1];
    const float* p  = (const float*)d_in[2];
    const float* Fx = (const float*)d_in[3];
    const float* Fy = (const float*)d_in[4];
    const float* k1 = (const float*)d_in[5];

    float* out = (float*)d_out;
    float* out_u = out;
    float* out_v = out + (size_t)NN2;
    float* out_p = out + 2 * (size_t)NN2;
    float* out_w = out + 3 * (size_t)NN2;
    float* out_r = out + 4 * (size_t)NN2;

    float* ws = (float*)d_ws;
    float* ku = ws;                 // also reused as the 2048^2 residual buffer
    float* kv = ws + (size_t)NN2;   // also reused as pB
    float* b  = ws + 2 * (size_t)NN2;
    float* pA = ws + 3 * (size_t)NN2;
    float* pB = kv;
    float* r1024 = ws + 4 * (size_t)NN2;
    float* r512  = r1024 + 1024 * 1024;
    float* r256  = r512 + 512 * 512;
    float* r128  = r256 + 256 * 256;
    float* w128  = r128 + 128 * 128;
    float* w256  = w128 + 128 * 128;
    float* w512  = w256 + 256 * 256;
    float* w1024 = w512 + 512 * 512;

    // b_u/b_v live in the not-yet-needed output regions (dead before w/p are produced)
    float* bu = out_w;
    float* bv = out_p;
    float* rs0 = ku;

    dim3 blk(64, 4);
    dim3 g2048(NN / 64, NN / 4);

    // momentum
    k_pg1<<<g2048, blk, 0, stream>>>(u, v, k1, ku, kv);
    k_pred<<<g2048, blk, 0, stream>>>(u, v, p, ku, kv, bu, bv);
    k_pg1<<<g2048, blk, 0, stream>>>(bu, bv, k1, ku, kv);
    k_corr<<<g2048, blk, 0, stream>>>(u, v, p, bu, bv, ku, kv, Fx, Fy, out_u, out_v);
    k_rhs<<<g2048, blk, 0, stream>>>(out_u, out_v, b);

    // multigrid F-cycle, 5 iterations
    const float* pcur = p;
    for (int it = 0; it < 5; ++it) {
        k_res<<<g2048, blk, 0, stream>>>(pcur, b, rs0);
        k_restrict2<<<dim3(8, 128), blk, 0, stream>>>(rs0, r1024, r512, 2048);
        k_restrict2<<<dim3(2, 32), blk, 0, stream>>>(r512, r256, r128, 512);
        k_small<<<1, 1024, 0, stream>>>(r128, w128, out_r);
        k_prolong<<<dim3(2, 32), blk, 0, stream>>>(w128, r128, w256, 128);
        k_prolong<<<dim3(4, 64), blk, 0, stream>>>(w256, r256, w512, 256);
        k_prolong<<<dim3(8, 128), blk, 0, stream>>>(w512, r512, w1024, 512);
        k_prolong<<<dim3(16, 256), blk, 0, stream>>>(w1024, r1024, out_w, 1024);
        float* pdst = (it == 4) ? out_p : ((it & 1) ? pB : pA);
        k_pupd<<<g2048, blk, 0, stream>>>(pcur, out_w, b, pdst);
        pcur = pdst;
    }

    // final projection with the new pressure (in-place pointwise on u/v)
    k_fcorr<<<g2048, blk, 0, stream>>>(out_p, out_u, out_v);
}

// Round 2
// 425.722 us; speedup vs baseline: 1.2381x; 1.2381x over previous
//
#include <hip/hip_runtime.h>

#define NN 2048
#define NN2 (NN * NN)

// ---- vector load helpers: 4 points per thread, j0 = 4*jt (16B aligned) ----
__device__ __forceinline__ void load6z(const float* __restrict__ A, int i, int j0, float a[6]) {
    // zero-pad row + cols j0-1..j0+4
    if ((unsigned)i >= (unsigned)NN) {
#pragma unroll
        for (int q = 0; q < 6; ++q) a[q] = 0.f;
        return;
    }
    const float* row = A + (size_t)i * NN;
    float4 c = *reinterpret_cast<const float4*>(row + j0);
    a[1] = c.x; a[2] = c.y; a[3] = c.z; a[4] = c.w;
    a[0] = (j0 > 0) ? row[j0 - 1] : 0.f;
    a[5] = (j0 + 4 < NN) ? row[j0 + 4] : 0.f;
}
__device__ __forceinline__ void load4z(const float* __restrict__ A, int i, int j0, float a[4]) {
    if ((unsigned)i >= (unsigned)NN) {
#pragma unroll
        for (int q = 0; q < 4; ++q) a[q] = 0.f;
        return;
    }
    float4 c = *reinterpret_cast<const float4*>(A + (size_t)i * NN + j0);
    a[0] = c.x; a[1] = c.y; a[2] = c.z; a[3] = c.w;
}
__device__ __forceinline__ void load6e(const float* __restrict__ A, int i, int j0, float a[6]) {
    // edge-clamp row + cols
    i = i < 0 ? 0 : (i > NN - 1 ? NN - 1 : i);
    const float* row = A + (size_t)i * NN;
    float4 c = *reinterpret_cast<const float4*>(row + j0);
    a[1] = c.x; a[2] = c.y; a[3] = c.z; a[4] = c.w;
    a[0] = (j0 > 0) ? row[j0 - 1] : c.x;
    a[5] = (j0 + 4 < NN) ? row[j0 + 4] : c.w;
}
__device__ __forceinline__ void load4e(const float* __restrict__ A, int i, int j0, float a[4]) {
    i = i < 0 ? 0 : (i > NN - 1 ? NN - 1 : i);
    float4 c = *reinterpret_cast<const float4*>(A + (size_t)i * NN + j0);
    a[0] = c.x; a[1] = c.y; a[2] = c.z; a[3] = c.w;
}
__device__ __forceinline__ void store4(float* __restrict__ A, int i, int j0, const float a[4]) {
    *reinterpret_cast<float4*>(A + (size_t)i * NN + j0) = make_float4(a[0], a[1], a[2], a[3]);
}

// ---------------- Petrov-Galerkin k coefficient ----------------
__global__ __launch_bounds__(256) void k_pg1_v(const float* __restrict__ u, const float* __restrict__ v,
                                               const float* __restrict__ k1,
                                               float* __restrict__ ku, float* __restrict__ kv) {
    int jt = blockIdx.x * blockDim.x + threadIdx.x;
    int i  = blockIdx.y * blockDim.y + threadIdx.y;
    int j0 = jt * 4;
    float u6[6], v6[6], uu[4], ud[4], vu[4], vd[4], kc[4], oku[4], okv[4];
    load6z(u, i, j0, u6); load6z(v, i, j0, v6);
    load4z(u, i - 1, j0, uu); load4z(u, i + 1, j0, ud);
    load4z(v, i - 1, j0, vu); load4z(v, i + 1, j0, vd);
    load4z(k1, i, j0, kc);
#pragma unroll
    for (int c = 0; c < 4; ++c) {
        float uc = u6[c + 1], ul = u6[c], ur = u6[c + 2], ut = uu[c], ub = ud[c];
        float vc = v6[c + 1], vl = v6[c], vr = v6[c + 2], vt = vu[c], vb = vd[c];
        float ADxu = 0.5f * (ur - ul), ADyu = 0.5f * (ub - ut);
        float ADxv = 0.5f * (vr - vl), ADyv = 0.5f * (vb - vt);
        float Lu = ul + ur + ut + ub - 4.f * uc;
        float Lv = vl + vr + vt + vb - 4.f * vc;
        float s = fabsf(uc) + fabsf(vc);
        float kuv = 0.25f * fabsf(0.5f * s * Lu) / (0.001f + 0.5f * (fabsf(ADxu) + fabsf(ADyu)));
        float kvv = 0.25f * fabsf(0.5f * s * Lv) / (0.001f + 0.5f * (fabsf(ADxv) + fabsf(ADyv)));
        oku[c] = fminf(kuv, kc[c]); okv[c] = fminf(kvv, kc[c]);
    }
    store4(ku, i, j0, oku); store4(kv, i, j0, okv);
}

// ---------------- predictor: b_u, b_v ----------------
__global__ __launch_bounds__(256) void k_pred_v(const float* __restrict__ u, const float* __restrict__ v,
                                                const float* __restrict__ p,
                                                const float* __restrict__ ku, const float* __restrict__ kv,
                                                float* __restrict__ bu, float* __restrict__ bv) {
    const float DT = 0.01f;
    int jt = blockIdx.x * blockDim.x + threadIdx.x;
    int i  = blockIdx.y * blockDim.y + threadIdx.y;
    int j0 = jt * 4;
    float u6[6], v6[6], uu[4], ud[4], vu[4], vd[4];
    float ku6[6], kv6[6], kuu[4], kud[4], kvu[4], kvd[4];
    float p6[6], pu[4], pd[4], obu[4], obv[4];
    load6z(u, i, j0, u6); load6z(v, i, j0, v6);
    load4z(u, i - 1, j0, uu); load4z(u, i + 1, j0, ud);
    load4z(v, i - 1, j0, vu); load4z(v, i + 1, j0, vd);
    load6z(ku, i, j0, ku6); load6z(kv, i, j0, kv6);
    load4z(ku, i - 1, j0, kuu); load4z(ku, i + 1, j0, kud);
    load4z(kv, i - 1, j0, kvu); load4z(kv, i + 1, j0, kvd);
    load6e(p, i, j0, p6); load4e(p, i - 1, j0, pu); load4e(p, i + 1, j0, pd);
#pragma unroll
    for (int c = 0; c < 4; ++c) {
        float uc = u6[c + 1], ul = u6[c], ur = u6[c + 2], ut = uu[c], ub = ud[c];
        float vc = v6[c + 1], vl = v6[c], vr = v6[c + 2], vt = vu[c], vb = vd[c];
        float kuc = ku6[c + 1], kul = ku6[c], kur = ku6[c + 2], kut = kuu[c], kub = kud[c];
        float kvc = kv6[c + 1], kvl = kv6[c], kvr = kv6[c + 2], kvt = kvu[c], kvb = kvd[c];
        float ADxu = 0.5f * (ur - ul), ADyu = 0.5f * (ub - ut);
        float ADxv = 0.5f * (vr - vl), ADyv = 0.5f * (vb - vt);
        float Lu = ul + ur + ut + ub - 4.f * uc;
        float Lv = vl + vr + vt + vb - 4.f * vc;
        float Lku = kul + kur + kut + kub - 4.f * kuc;
        float Lkv = kvl + kvr + kvt + kvb - 4.f * kvc;
        float Luku = ul * kul + ur * kur + ut * kut + ub * kub - 4.f * uc * kuc;
        float Lvkv = vl * kvl + vr * kvr + vt * kvt + vb * kvb - 4.f * vc * kvc;
        float kx = 1.5f * (kuc * Lu + Luku - uc * Lku);
        float ky = 1.5f * (kvc * Lv + Lvkv - vc * Lkv);
        float Grapx = 0.5f * (p6[c + 2] - p6[c]) * DT;
        float Grapy = 0.5f * (pd[c] - pu[c]) * DT;
        obu[c] = uc + 0.5f * (kx * DT - uc * ADxu * DT - vc * ADyu * DT) - Grapx;
        obv[c] = vc + 0.5f * (ky * DT - uc * ADxv * DT - vc * ADyv * DT) - Grapy;
    }
    store4(bu, i, j0, obu); store4(bv, i, j0, obv);
}

// ---------------- corrector: u_new, v_new ----------------
__global__ __launch_bounds__(256) void k_corr_v(const float* __restrict__ u, const float* __restrict__ v,
                                                const float* __restrict__ p,
                                                const float* __restrict__ bu, const float* __restrict__ bv,
                                                const float* __restrict__ ku, const float* __restrict__ kv,
                                                const float* __restrict__ Fx, const float* __restrict__ Fy,
                                                float* __restrict__ un, float* __restrict__ vn) {
    const float DT = 0.01f;
    int jt = blockIdx.x * blockDim.x + threadIdx.x;
    int i  = blockIdx.y * blockDim.y + threadIdx.y;
    int j0 = jt * 4;
    float u6[6], v6[6], uu[4], ud[4], vu[4], vd[4];
    float bu6[6], bv6[6], buu[4], bud[4], bvu[4], bvd[4];
    float ku6[6], kv6[6], kuu[4], kud[4], kvu[4], kvd[4];
    float p6[6], pu[4], pd[4], fx[4], fy[4], oun[4], ovn[4];
    load6z(u, i, j0, u6); load6z(v, i, j0, v6);
    load4z(u, i - 1, j0, uu); load4z(u, i + 1, j0, ud);
    load4z(v, i - 1, j0, vu); load4z(v, i + 1, j0, vd);
    load6z(bu, i, j0, bu6); load6z(bv, i, j0, bv6);
    load4z(bu, i - 1, j0, buu); load4z(bu, i + 1, j0, bud);
    load4z(bv, i - 1, j0, bvu); load4z(bv, i + 1, j0, bvd);
    load6z(ku, i, j0, ku6); load6z(kv, i, j0, kv6);
    load4z(ku, i - 1, j0, kuu); load4z(ku, i + 1, j0, kud);
    load4z(kv, i - 1, j0, kvu); load4z(kv, i + 1, j0, kvd);
    load6e(p, i, j0, p6); load4e(p, i - 1, j0, pu); load4e(p, i + 1, j0, pd);
    load4z(Fx, i, j0, fx); load4z(Fy, i, j0, fy);
#pragma unroll
    for (int c = 0; c < 4; ++c) {
        float uc = u6[c + 1], ul = u6[c], ur = u6[c + 2], ut = uu[c], ub = ud[c];
        float vc = v6[c + 1], vl = v6[c], vr = v6[c + 2], vt = vu[c], vb = vd[c];
        float buc = bu6[c + 1], bul = bu6[c], bur = bu6[c + 2], but = buu[c], bub = bud[c];
        float bvc = bv6[c + 1], bvl = bv6[c], bvr = bv6[c + 2], bvt = bvu[c], bvb = bvd[c];
        float kuc = ku6[c + 1], kul = ku6[c], kur = ku6[c + 2], kut = kuu[c], kub = kud[c];
        float kvc = kv6[c + 1], kvl = kv6[c], kvr = kv6[c + 2], kvt = kvu[c], kvb = kvd[c];
        float ADxbu = 0.5f * (bur - bul), ADybu = 0.5f * (bub - but);
        float ADxbv = 0.5f * (bvr - bvl), ADybv = 0.5f * (bvb - bvt);
        float Lbu = bul + bur + but + bub - 4.f * buc;
        float Lbv = bvl + bvr + bvt + bvb - 4.f * bvc;
        float Lku = kul + kur + kut + kub - 4.f * kuc;
        float Lkv = kvl + kvr + kvt + kvb - 4.f * kvc;
        // product term uses the ORIGINAL velocities (torch closes over values_uu/vv)
        float Luku = ul * kul + ur * kur + ut * kut + ub * kub - 4.f * uc * kuc;
        float Lvkv = vl * kvl + vr * kvr + vt * kvt + vb * kvb - 4.f * vc * kvc;
        float kx = 1.5f * (kuc * Lbu + Luku - buc * Lku);
        float ky = 1.5f * (kvc * Lbv + Lvkv - bvc * Lkv);
        float Grapx = 0.5f * (p6[c + 2] - p6[c]) * DT;
        float Grapy = 0.5f * (pd[c] - pu[c]) * DT;
        oun[c] = uc + kx * DT - buc * ADxbu * DT - bvc * ADybu * DT - Grapx - fx[c] * DT;
        ovn[c] = vc + ky * DT - buc * ADxbv * DT - bvc * ADybv * DT - Grapy - fy[c] * DT;
    }
    store4(un, i, j0, oun); store4(vn, i, j0, ovn);
}

// ---------------- pressure RHS: b = -div(u_new)/DT ----------------
__global__ __launch_bounds__(256) void k_rhs_v(const float* __restrict__ un, const float* __restrict__ vn,
                                               float* __restrict__ b) {
    const float INVDT = 100.0f;
    int jt = blockIdx.x * blockDim.x + threadIdx.x;
    int i  = blockIdx.y * blockDim.y + threadIdx.y;
    int j0 = jt * 4;
    float u6[6], vu[4], vd[4], ob[4];
    load6z(un, i, j0, u6);
    load4z(vn, i - 1, j0, vu); load4z(vn, i + 1, j0, vd);
#pragma unroll
    for (int c = 0; c < 4; ++c) {
        float adx = 0.5f * (u6[c + 2] - u6[c]);
        float ady = 0.5f * (vd[c] - vu[c]);
        ob[c] = -(adx + ady) * INVDT;
    }
    store4(b, i, j0, ob);
}

// ---------------- fused residual + restrict to 1024 and 512 ----------------
__global__ __launch_bounds__(256) void k_resrestrict(const float* __restrict__ p, const float* __restrict__ b,
                                                     float* __restrict__ r1024, float* __restrict__ r512) {
    int jt = blockIdx.x * blockDim.x + threadIdx.x;  // [0,512)
    int it = blockIdx.y * blockDim.y + threadIdx.y;  // [0,512)
    int j0 = jt * 4, i0 = it * 4;
    float p6[6][6];
#pragma unroll
    for (int r = 0; r < 6; ++r) load6e(p, i0 - 1 + r, j0, p6[r]);
    float res[4][4];
#pragma unroll
    for (int r = 0; r < 4; ++r) {
        float bb[4];
        load4z(b, i0 + r, j0, bb);
#pragma unroll
        for (int c = 0; c < 4; ++c) {
            float pc = p6[r + 1][c + 1];
            float nb = p6[r][c + 1] + p6[r + 2][c + 1] + p6[r + 1][c] + p6[r + 1][c + 2];
            res[r][c] = nb - 4.f * pc - bb[c];
        }
    }
    float q00 = 0.25f * (res[0][0] + res[0][1] + res[1][0] + res[1][1]);
    float q01 = 0.25f * (res[0][2] + res[0][3] + res[1][2] + res[1][3]);
    float q10 = 0.25f * (res[2][0] + res[2][1] + res[3][0] + res[3][1]);
    float q11 = 0.25f * (res[2][2] + res[2][3] + res[3][2] + res[3][3]);
    int ci = it * 2, cj = jt * 2;
    *reinterpret_cast<float2*>(r1024 + (size_t)ci * 1024 + cj)       = make_float2(q00, q01);
    *reinterpret_cast<float2*>(r1024 + (size_t)(ci + 1) * 1024 + cj) = make_float2(q10, q11);
    r512[(size_t)it * 512 + jt] = 0.25f * (q00 + q01 + q10 + q11);
}

// ---------------- fused 2-level restriction (512 -> 256 -> 128) ----------------
__global__ __launch_bounds__(256) void k_restrict2(const float* __restrict__ src,
                                                   float* __restrict__ dst1, float* __restrict__ dst2,
                                                   int n_src) {
    int j = blockIdx.x * blockDim.x + threadIdx.x;
    int i = blockIdx.y * blockDim.y + threadIdx.y;
    int n4 = n_src >> 2;
    int n2 = n_src >> 1;
    const float4* r0 = reinterpret_cast<const float4*>(src + (4 * i + 0) * n_src + 4 * j);
    const float4* r1 = reinterpret_cast<const float4*>(src + (4 * i + 1) * n_src + 4 * j);
    const float4* r2 = reinterpret_cast<const float4*>(src + (4 * i + 2) * n_src + 4 * j);
    const float4* r3 = reinterpret_cast<const float4*>(src + (4 * i + 3) * n_src + 4 * j);
    float4 a0 = *r0, a1 = *r1, a2 = *r2, a3 = *r3;
    float s00 = a0.x + a0.y + a1.x + a1.y;
    float s01 = a0.z + a0.w + a1.z + a1.w;
    float s10 = a2.x + a2.y + a3.x + a3.y;
    float s11 = a2.z + a2.w + a3.z + a3.w;
    *reinterpret_cast<float2*>(dst1 + (2 * i) * n2 + 2 * j)     = make_float2(0.25f * s00, 0.25f * s01);
    *reinterpret_cast<float2*>(dst1 + (2 * i + 1) * n2 + 2 * j) = make_float2(0.25f * s10, 0.25f * s11);
    dst2[i * n4 + j] = 0.0625f * (s00 + s01 + s10 + s11);
}

// ---------------- all coarse levels (<=128) in one block ----------------
__global__ __launch_bounds__(1024) void k_small(const float* __restrict__ r128,
                                                float* __restrict__ w128_out,
                                                float* __restrict__ r2_out) {
    __shared__ float sr64[64 * 64];
    __shared__ float sr32[32 * 32];
    __shared__ float sr16[16 * 16];
    __shared__ float sr8[8 * 8];
    __shared__ float sr4[16];
    __shared__ float sr2[4];
    __shared__ float wa[64 * 64];
    __shared__ float wb[64 * 64];
    int t = threadIdx.x;

    for (int idx = t; idx < 64 * 64; idx += 1024) {
        int i = idx >> 6, j = idx & 63;
        const float* s0 = r128 + (2 * i) * 128 + 2 * j;
        sr64[idx] = 0.25f * (s0[0] + s0[1] + s0[128] + s0[129]);
    }
    __syncthreads();
    if (t < 32 * 32) {
        int i = t >> 5, j = t & 31;
        const float* s0 = sr64 + (2 * i) * 64 + 2 * j;
        sr32[t] = 0.25f * (s0[0] + s0[1] + s0[64] + s0[65]);
    }
    __syncthreads();
    if (t < 16 * 16) {
        int i = t >> 4, j = t & 15;
        const float* s0 = sr32 + (2 * i) * 32 + 2 * j;
        sr16[t] = 0.25f * (s0[0] + s0[1] + s0[32] + s0[33]);
    }
    __syncthreads();
    if (t < 64) {
        int i = t >> 3, j = t & 7;
        const float* s0 = sr16 + (2 * i) * 16 + 2 * j;
        sr8[t] = 0.25f * (s0[0] + s0[1] + s0[16] + s0[17]);
    }
    __syncthreads();
    if (t < 16) {
        int i = t >> 2, j = t & 3;
        const float* s0 = sr8 + (2 * i) * 8 + 2 * j;
        sr4[t] = 0.25f * (s0[0] + s0[1] + s0[8] + s0[9]);
    }
    __syncthreads();
    if (t < 4) {
        int i = t >> 1, j = t & 1;
        const float* s0 = sr4 + (2 * i) * 4 + 2 * j;
        sr2[t] = 0.25f * (s0[0] + s0[1] + s0[4] + s0[5]);
        r2_out[t] = sr2[t];
        float ws = -0.25f * sr2[t];
        wa[(2 * i) * 4 + 2 * j] = ws;
        wa[(2 * i) * 4 + 2 * j + 1] = ws;
        wa[(2 * i + 1) * 4 + 2 * j] = ws;
        wa[(2 * i + 1) * 4 + 2 * j + 1] = ws;
    }
    __syncthreads();

    auto step = [&](const float* win, const float* rl, float* wout, int s) {
        for (int idx = t; idx < s * s; idx += 1024) {
            int i = idx / s, j = idx - i * s;
            float up = i > 0 ? win[(i - 1) * s + j] : 0.f;
            float dn = i < s - 1 ? win[(i + 1) * s + j] : 0.f;
            float lf = j > 0 ? win[i * s + j - 1] : 0.f;
            float rt = j < s - 1 ? win[i * s + j + 1] : 0.f;
            float ws = 0.25f * (up + dn + lf + rt - rl[idx]);
            int o = 2 * s;
            wout[(2 * i) * o + 2 * j] = ws;
            wout[(2 * i) * o + 2 * j + 1] = ws;
            wout[(2 * i + 1) * o + 2 * j] = ws;
            wout[(2 * i + 1) * o + 2 * j + 1] = ws;
        }
    };
    step(wa, sr4, wb, 4);
    __syncthreads();
    step(wb, sr8, wa, 8);
    __syncthreads();
    step(wa, sr16, wb, 16);
    __syncthreads();
    step(wb, sr32, wa, 32);
    __syncthreads();
    step(wa, sr64, w128_out, 64);
}

// ---------------- smooth + upsample, one mid level ----------------
__global__ __launch_bounds__(256) void k_prolong(const float* __restrict__ win, const float* __restrict__ rl,
                                                 float* __restrict__ wout, int n) {
    int j = blockIdx.x * blockDim.x + threadIdx.x;
    int i = blockIdx.y * blockDim.y + threadIdx.y;
    float up = i > 0 ? win[(i - 1) * n + j] : 0.f;
    float dn = i < n - 1 ? win[(i + 1) * n + j] : 0.f;
    float lf = j > 0 ? win[i * n + j - 1] : 0.f;
    float rt = j < n - 1 ? win[i * n + j + 1] : 0.f;
    float ws = 0.25f * (up + dn + lf + rt - rl[i * n + j]);
    int o = 2 * n;
    float2 vv = make_float2(ws, ws);
    *reinterpret_cast<float2*>(wout + (2 * i) * o + 2 * j) = vv;
    *reinterpret_cast<float2*>(wout + (2 * i + 1) * o + 2 * j) = vv;
}

// -------- fused: smooth w1024 -> (implicit w2048) -> p update (+ optional out_w) --------
template <bool LAST>
__global__ __launch_bounds__(256) void k_pupd_f(const float* __restrict__ p, const float* __restrict__ b,
                                                const float* __restrict__ w1024, const float* __restrict__ r1024,
                                                float* __restrict__ pdst, float* __restrict__ wout) {
    __shared__ float ws[4][130];
    const int jb = blockIdx.x * 256;   // fine col base (64 threads * 4)
    const int ib = blockIdx.y * 4;     // fine row base
    const int cr_base = ib / 2 - 1;
    const int cc_base = jb / 2 - 1;
    const int tid = threadIdx.y * 64 + threadIdx.x;

    // build smoothed-coarse tile: ws = 0.25*(zero-pad nbrsum(w1024) - r1024)
    for (int cell = tid; cell < 4 * 130; cell += 256) {
        int r = cell / 130, c = cell - r * 130;
        int ci = cr_base + r, cj = cc_base + c;
        float val = 0.f;
        if ((unsigned)ci < 1024u && (unsigned)cj < 1024u) {
            const float* wr = w1024 + (size_t)ci * 1024;
            float up = ci > 0    ? wr[cj - 1024] : 0.f;
            float dn = ci < 1023 ? wr[cj + 1024] : 0.f;
            float lf = cj > 0    ? wr[cj - 1] : 0.f;
            float rt = cj < 1023 ? wr[cj + 1] : 0.f;
            val = 0.25f * (up + dn + lf + rt - r1024[(size_t)ci * 1024 + cj]);
        }
        ws[r][c] = val;
    }
    __syncthreads();

    const int i  = ib + threadIdx.y;
    const int j0 = jb + threadIdx.x * 4;
    float p6[6], pu[4], pd[4], bb[4], op[4];
    load6e(p, i, j0, p6);
    load4e(p, i - 1, j0, pu);
    load4e(p, i + 1, j0, pd);
    load4z(b, i, j0, bb);

    const int iu = (i - 1) < 0 ? 0 : (i - 1);
    const int id = (i + 1) > NN - 1 ? NN - 1 : (i + 1);
    const int lrC = (i >> 1) - cr_base;
    const int lrU = (iu >> 1) - cr_base;
    const int lrD = (id >> 1) - cr_base;

#pragma unroll
    for (int c = 0; c < 4; ++c) {
        int f = j0 + c;
        int fl = (f - 1) < 0 ? 0 : (f - 1);
        int fr = (f + 1) > NN - 1 ? NN - 1 : (f + 1);
        float pml = p6[c]     - ws[lrC][(fl >> 1) - cc_base];
        float pmr = p6[c + 2] - ws[lrC][(fr >> 1) - cc_base];
        float pmt = pu[c]     - ws[lrU][(f >> 1) - cc_base];
        float pmb = pd[c]     - ws[lrD][(f >> 1) - cc_base];
        op[c] = 0.25f * (pml + pmr + pmt + pmb - bb[c]);
    }
    store4(pdst, i, j0, op);
    if (LAST) {
        float ow[4];
#pragma unroll
        for (int c = 0; c < 4; ++c) ow[c] = ws[lrC][((j0 + c) >> 1) - cc_base];
        store4(wout, i, j0, ow);
    }
}

// ---------------- final projection ----------------
__global__ __launch_bounds__(256) void k_fcorr_v(const float* __restrict__ p,
                                                 float* __restrict__ un, float* __restrict__ vn) {
    const float DT = 0.01f;
    int jt = blockIdx.x * blockDim.x + threadIdx.x;
    int i  = blockIdx.y * blockDim.y + threadIdx.y;
    int j0 = jt * 4;
    float p6[6], pu[4], pd[4];
    load6e(p, i, j0, p6);
    load4e(p, i - 1, j0, pu);
    load4e(p, i + 1, j0, pd);
    float4 uc = *reinterpret_cast<float4*>(un + (size_t)i * NN + j0);
    float4 vc = *reinterpret_cast<float4*>(vn + (size_t)i * NN + j0);
    float ou[4] = {uc.x, uc.y, uc.z, uc.w};
    float ov[4] = {vc.x, vc.y, vc.z, vc.w};
#pragma unroll
    for (int c = 0; c < 4; ++c) {
        ou[c] -= 0.5f * (p6[c + 2] - p6[c]) * DT;
        ov[c] -= 0.5f * (pd[c] - pu[c]) * DT;
    }
    store4(un, i, j0, ou);
    store4(vn, i, j0, ov);
}

extern "C" void kernel_launch(void* const* d_in, const int* in_sizes, int n_in,
                              void* d_out, int out_size, void* d_ws, size_t ws_size,
                              hipStream_t stream) {
    const float* u  = (const float*)d_in[0];
    const float* v  = (const float*)d_in[1];
    const float* p  = (const float*)d_in[2];
    const float* Fx = (const float*)d_in[3];
    const float* Fy = (const float*)d_in[4];
    const float* k1 = (const float*)d_in[5];

    float* out = (float*)d_out;
    float* out_u = out;
    float* out_v = out + (size_t)NN2;
    float* out_p = out + 2 * (size_t)NN2;
    float* out_w = out + 3 * (size_t)NN2;
    float* out_r = out + 4 * (size_t)NN2;

    float* ws = (float*)d_ws;
    float* ku = ws;
    float* kv = ws + (size_t)NN2;    // reused as pB
    float* b  = ws + 2 * (size_t)NN2;
    float* pA = ws + 3 * (size_t)NN2;
    float* pB = kv;
    float* r1024 = ws + 4 * (size_t)NN2;
    float* r512  = r1024 + 1024 * 1024;
    float* r256  = r512 + 512 * 512;
    float* r128  = r256 + 256 * 256;
    float* w128  = r128 + 128 * 128;
    float* w256  = w128 + 128 * 128;
    float* w512  = w256 + 256 * 256;
    float* w1024 = w512 + 512 * 512;

    // b_u/b_v live in not-yet-needed output regions (dead before w/p are produced)
    float* bu = out_w;
    float* bv = out_p;

    dim3 blk(64, 4);
    dim3 g4(8, 512);     // 2048^2, 4 pts/thread in x

    // momentum
    k_pg1_v<<<g4, blk, 0, stream>>>(u, v, k1, ku, kv);
    k_pred_v<<<g4, blk, 0, stream>>>(u, v, p, ku, kv, bu, bv);
    k_pg1_v<<<g4, blk, 0, stream>>>(bu, bv, k1, ku, kv);
    k_corr_v<<<g4, blk, 0, stream>>>(u, v, p, bu, bv, ku, kv, Fx, Fy, out_u, out_v);
    k_rhs_v<<<g4, blk, 0, stream>>>(out_u, out_v, b);

    // multigrid F-cycle, 5 iterations
    const float* pcur = p;
    for (int it = 0; it < 5; ++it) {
        k_resrestrict<<<dim3(8, 128), blk, 0, stream>>>(pcur, b, r1024, r512);
        k_restrict2<<<dim3(2, 32), blk, 0, stream>>>(r512, r256, r128, 512);
        k_small<<<1, 1024, 0, stream>>>(r128, w128, out_r);
        k_prolong<<<dim3(2, 32), blk, 0, stream>>>(w128, r128, w256, 128);
        k_prolong<<<dim3(4, 64), blk, 0, stream>>>(w256, r256, w512, 256);
        k_prolong<<<dim3(8, 128), blk, 0, stream>>>(w512, r512, w1024, 512);
        if (it < 4) {
            float* pdst = (it & 1) ? pB : pA;
            k_pupd_f<false><<<dim3(8, 512), blk, 0, stream>>>(pcur, b, w1024, r1024, pdst, nullptr);
            pcur = pdst;
        } else {
            k_pupd_f<true><<<dim3(8, 512), blk, 0, stream>>>(pcur, b, w1024, r1024, out_p, out_w);
        }
    }

    // final projection with the new pressure
    k_fcorr_v<<<g4, blk, 0, stream>>>(out_p, out_u, out_v);
}

// Round 3
// 400.799 us; speedup vs baseline: 1.3151x; 1.0622x over previous
//
#include <hip/hip_runtime.h>

#define NN 2048
#define NN2 (NN * NN)

// ---- vector load helpers: 4 points per thread, j0 = 4*jt (16B aligned) ----
__device__ __forceinline__ void load6z(const float* __restrict__ A, int i, int j0, float a[6]) {
    if ((unsigned)i >= (unsigned)NN) {
#pragma unroll
        for (int q = 0; q < 6; ++q) a[q] = 0.f;
        return;
    }
    const float* row = A + (size_t)i * NN;
    float4 c = *reinterpret_cast<const float4*>(row + j0);
    a[1] = c.x; a[2] = c.y; a[3] = c.z; a[4] = c.w;
    a[0] = (j0 > 0) ? row[j0 - 1] : 0.f;
    a[5] = (j0 + 4 < NN) ? row[j0 + 4] : 0.f;
}
__device__ __forceinline__ void load4z(const float* __restrict__ A, int i, int j0, float a[4]) {
    if ((unsigned)i >= (unsigned)NN) {
#pragma unroll
        for (int q = 0; q < 4; ++q) a[q] = 0.f;
        return;
    }
    float4 c = *reinterpret_cast<const float4*>(A + (size_t)i * NN + j0);
    a[0] = c.x; a[1] = c.y; a[2] = c.z; a[3] = c.w;
}
__device__ __forceinline__ void load6e(const float* __restrict__ A, int i, int j0, float a[6]) {
    i = i < 0 ? 0 : (i > NN - 1 ? NN - 1 : i);
    const float* row = A + (size_t)i * NN;
    float4 c = *reinterpret_cast<const float4*>(row + j0);
    a[1] = c.x; a[2] = c.y; a[3] = c.z; a[4] = c.w;
    a[0] = (j0 > 0) ? row[j0 - 1] : c.x;
    a[5] = (j0 + 4 < NN) ? row[j0 + 4] : c.w;
}
__device__ __forceinline__ void load4e(const float* __restrict__ A, int i, int j0, float a[4]) {
    i = i < 0 ? 0 : (i > NN - 1 ? NN - 1 : i);
    float4 c = *reinterpret_cast<const float4*>(A + (size_t)i * NN + j0);
    a[0] = c.x; a[1] = c.y; a[2] = c.z; a[3] = c.w;
}
__device__ __forceinline__ void store4(float* __restrict__ A, int i, int j0, const float a[4]) {
    *reinterpret_cast<float4*>(A + (size_t)i * NN + j0) = make_float4(a[0], a[1], a[2], a[3]);
}

// ===================== fused pg1 + predictor =====================
// tile: 32 rows x 64 cols center; stage u,v with 2-halo; k computed into LDS.
__global__ __launch_bounds__(256) void k_pred_f(const float* __restrict__ u, const float* __restrict__ v,
                                                const float* __restrict__ k1, const float* __restrict__ p,
                                                float* __restrict__ bu, float* __restrict__ bv) {
    const float DT = 0.01f;
    __shared__ __align__(16) float su[36][72], sv[36][72];
    __shared__ float sku[34][68], skv[34][68];
    const int jb = blockIdx.x * 64;
    const int ib = blockIdx.y * 32;
    const int tid = threadIdx.y * 16 + threadIdx.x;

    // stage u,v rows ib-2..ib+33, cols jb-4..jb+67 (zero-pad)
    for (int idx = tid; idx < 36 * 18; idx += 256) {
        int r = idx / 18, c4 = idx - r * 18;
        int gi = ib - 2 + r;
        int gj = jb - 4 + c4 * 4;
        float4 uu = make_float4(0.f, 0.f, 0.f, 0.f), vv = uu;
        if ((unsigned)gi < (unsigned)NN) {
            if (gj >= 0 && gj + 3 < NN) {
                uu = *reinterpret_cast<const float4*>(u + (size_t)gi * NN + gj);
                vv = *reinterpret_cast<const float4*>(v + (size_t)gi * NN + gj);
            } else {
                float tu[4], tv[4];
#pragma unroll
                for (int q = 0; q < 4; ++q) {
                    int g = gj + q;
                    bool in = (unsigned)g < (unsigned)NN;
                    tu[q] = in ? u[(size_t)gi * NN + g] : 0.f;
                    tv[q] = in ? v[(size_t)gi * NN + g] : 0.f;
                }
                uu = make_float4(tu[0], tu[1], tu[2], tu[3]);
                vv = make_float4(tv[0], tv[1], tv[2], tv[3]);
            }
        }
        *reinterpret_cast<float4*>(&su[r][c4 * 4]) = uu;
        *reinterpret_cast<float4*>(&sv[r][c4 * 4]) = vv;
    }
    __syncthreads();

    // k on rows ib-1..ib+32 (34), cols jb-1..jb+64 (66)
    for (int idx = tid; idx < 34 * 66; idx += 256) {
        int r = idx / 66, c = idx - r * 66;
        int gi = ib - 1 + r, gj = jb - 1 + c;
        float kuo = 0.f, kvo = 0.f;
        if ((unsigned)gi < (unsigned)NN && (unsigned)gj < (unsigned)NN) {
            int lr = r + 1, lc = c + 3;
            float uc = su[lr][lc], ul = su[lr][lc - 1], ur = su[lr][lc + 1], ut = su[lr - 1][lc], ub = su[lr + 1][lc];
            float vc = sv[lr][lc], vl = sv[lr][lc - 1], vr = sv[lr][lc + 1], vt = sv[lr - 1][lc], vb = sv[lr + 1][lc];
            float ADxu = 0.5f * (ur - ul), ADyu = 0.5f * (ub - ut);
            float ADxv = 0.5f * (vr - vl), ADyv = 0.5f * (vb - vt);
            float Lu = ul + ur + ut + ub - 4.f * uc;
            float Lv = vl + vr + vt + vb - 4.f * vc;
            float s = fabsf(uc) + fabsf(vc);
            float kuv = 0.25f * fabsf(0.5f * s * Lu) / (0.001f + 0.5f * (fabsf(ADxu) + fabsf(ADyu)));
            float kvv = 0.25f * fabsf(0.5f * s * Lv) / (0.001f + 0.5f * (fabsf(ADxv) + fabsf(ADyv)));
            float k1c = k1[(size_t)gi * NN + gj];
            kuo = fminf(kuv, k1c);
            kvo = fminf(kvv, k1c);
        }
        sku[r][c] = kuo;
        skv[r][c] = kvo;
    }
    __syncthreads();

    const int i0 = ib + threadIdx.y * 2;
    const int j0 = jb + threadIdx.x * 4;
#pragma unroll
    for (int a = 0; a < 2; ++a) {
        int i = i0 + a;
        float p6[6], pu[4], pd[4], obu[4], obv[4];
        load6e(p, i, j0, p6); load4e(p, i - 1, j0, pu); load4e(p, i + 1, j0, pd);
        int lur = i - ib + 2, lkr = i - ib + 1;
#pragma unroll
        for (int c = 0; c < 4; ++c) {
            int luc = j0 + c - jb + 4, lkc = j0 + c - jb + 1;
            float uc = su[lur][luc], ul = su[lur][luc - 1], ur = su[lur][luc + 1], ut = su[lur - 1][luc], ub = su[lur + 1][luc];
            float vc = sv[lur][luc], vl = sv[lur][luc - 1], vr = sv[lur][luc + 1], vt = sv[lur - 1][luc], vb = sv[lur + 1][luc];
            float kuc = sku[lkr][lkc], kul = sku[lkr][lkc - 1], kur = sku[lkr][lkc + 1], kut = sku[lkr - 1][lkc], kub = sku[lkr + 1][lkc];
            float kvc = skv[lkr][lkc], kvl = skv[lkr][lkc - 1], kvr = skv[lkr][lkc + 1], kvt = skv[lkr - 1][lkc], kvb = skv[lkr + 1][lkc];
            float ADxu = 0.5f * (ur - ul), ADyu = 0.5f * (ub - ut);
            float ADxv = 0.5f * (vr - vl), ADyv = 0.5f * (vb - vt);
            float Lu = ul + ur + ut + ub - 4.f * uc;
            float Lv = vl + vr + vt + vb - 4.f * vc;
            float Lku = kul + kur + kut + kub - 4.f * kuc;
            float Lkv = kvl + kvr + kvt + kvb - 4.f * kvc;
            float Luku = ul * kul + ur * kur + ut * kut + ub * kub - 4.f * uc * kuc;
            float Lvkv = vl * kvl + vr * kvr + vt * kvt + vb * kvb - 4.f * vc * kvc;
            float kx = 1.5f * (kuc * Lu + Luku - uc * Lku);
            float ky = 1.5f * (kvc * Lv + Lvkv - vc * Lkv);
            float Grapx = 0.5f * (p6[c + 2] - p6[c]) * DT;
            float Grapy = 0.5f * (pd[c] - pu[c]) * DT;
            obu[c] = uc + 0.5f * (kx * DT - uc * ADxu * DT - vc * ADyu * DT) - Grapx;
            obv[c] = vc + 0.5f * (ky * DT - uc * ADxv * DT - vc * ADyv * DT) - Grapy;
        }
        store4(bu, i, j0, obu);
        store4(bv, i, j0, obv);
    }
}

// ===================== fused pg1(b) + corrector =====================
__global__ __launch_bounds__(256) void k_corr_f(const float* __restrict__ u, const float* __restrict__ v,
                                                const float* __restrict__ k1, const float* __restrict__ p,
                                                const float* __restrict__ bu, const float* __restrict__ bv,
                                                const float* __restrict__ Fx, const float* __restrict__ Fy,
                                                float* __restrict__ un, float* __restrict__ vn) {
    const float DT = 0.01f;
    __shared__ __align__(16) float sbu[36][72], sbv[36][72];
    __shared__ float sku[34][68], skv[34][68];
    const int jb = blockIdx.x * 64;
    const int ib = blockIdx.y * 32;
    const int tid = threadIdx.y * 16 + threadIdx.x;

    for (int idx = tid; idx < 36 * 18; idx += 256) {
        int r = idx / 18, c4 = idx - r * 18;
        int gi = ib - 2 + r;
        int gj = jb - 4 + c4 * 4;
        float4 uu = make_float4(0.f, 0.f, 0.f, 0.f), vv = uu;
        if ((unsigned)gi < (unsigned)NN) {
            if (gj >= 0 && gj + 3 < NN) {
                uu = *reinterpret_cast<const float4*>(bu + (size_t)gi * NN + gj);
                vv = *reinterpret_cast<const float4*>(bv + (size_t)gi * NN + gj);
            } else {
                float tu[4], tv[4];
#pragma unroll
                for (int q = 0; q < 4; ++q) {
                    int g = gj + q;
                    bool in = (unsigned)g < (unsigned)NN;
                    tu[q] = in ? bu[(size_t)gi * NN + g] : 0.f;
                    tv[q] = in ? bv[(size_t)gi * NN + g] : 0.f;
                }
                uu = make_float4(tu[0], tu[1], tu[2], tu[3]);
                vv = make_float4(tv[0], tv[1], tv[2], tv[3]);
            }
        }
        *reinterpret_cast<float4*>(&sbu[r][c4 * 4]) = uu;
        *reinterpret_cast<float4*>(&sbv[r][c4 * 4]) = vv;
    }
    __syncthreads();

    // k from (bu,bv)
    for (int idx = tid; idx < 34 * 66; idx += 256) {
        int r = idx / 66, c = idx - r * 66;
        int gi = ib - 1 + r, gj = jb - 1 + c;
        float kuo = 0.f, kvo = 0.f;
        if ((unsigned)gi < (unsigned)NN && (unsigned)gj < (unsigned)NN) {
            int lr = r + 1, lc = c + 3;
            float uc = sbu[lr][lc], ul = sbu[lr][lc - 1], ur = sbu[lr][lc + 1], ut = sbu[lr - 1][lc], ub = sbu[lr + 1][lc];
            float vc = sbv[lr][lc], vl = sbv[lr][lc - 1], vr = sbv[lr][lc + 1], vt = sbv[lr - 1][lc], vb = sbv[lr + 1][lc];
            float ADxu = 0.5f * (ur - ul), ADyu = 0.5f * (ub - ut);
            float ADxv = 0.5f * (vr - vl), ADyv = 0.5f * (vb - vt);
            float Lu = ul + ur + ut + ub - 4.f * uc;
            float Lv = vl + vr + vt + vb - 4.f * vc;
            float s = fabsf(uc) + fabsf(vc);
            float kuv = 0.25f * fabsf(0.5f * s * Lu) / (0.001f + 0.5f * (fabsf(ADxu) + fabsf(ADyu)));
            float kvv = 0.25f * fabsf(0.5f * s * Lv) / (0.001f + 0.5f * (fabsf(ADxv) + fabsf(ADyv)));
            float k1c = k1[(size_t)gi * NN + gj];
            kuo = fminf(kuv, k1c);
            kvo = fminf(kvv, k1c);
        }
        sku[r][c] = kuo;
        skv[r][c] = kvo;
    }
    __syncthreads();

    const int i0 = ib + threadIdx.y * 2;
    const int j0 = jb + threadIdx.x * 4;
#pragma unroll
    for (int a = 0; a < 2; ++a) {
        int i = i0 + a;
        float p6[6], pu[4], pd[4];
        float u6[6], uu[4], ud[4], v6[6], vu[4], vd[4], fx[4], fy[4], oun[4], ovn[4];
        load6e(p, i, j0, p6); load4e(p, i - 1, j0, pu); load4e(p, i + 1, j0, pd);
        load6z(u, i, j0, u6); load4z(u, i - 1, j0, uu); load4z(u, i + 1, j0, ud);
        load6z(v, i, j0, v6); load4z(v, i - 1, j0, vu); load4z(v, i + 1, j0, vd);
        load4z(Fx, i, j0, fx); load4z(Fy, i, j0, fy);
        int lbr = i - ib + 2, lkr = i - ib + 1;
#pragma unroll
        for (int c = 0; c < 4; ++c) {
            int lbc = j0 + c - jb + 4, lkc = j0 + c - jb + 1;
            float buc = sbu[lbr][lbc], bul = sbu[lbr][lbc - 1], bur = sbu[lbr][lbc + 1], but = sbu[lbr - 1][lbc], bub = sbu[lbr + 1][lbc];
            float bvc = sbv[lbr][lbc], bvl = sbv[lbr][lbc - 1], bvr = sbv[lbr][lbc + 1], bvt = sbv[lbr - 1][lbc], bvb = sbv[lbr + 1][lbc];
            float kuc = sku[lkr][lkc], kul = sku[lkr][lkc - 1], kur = sku[lkr][lkc + 1], kut = sku[lkr - 1][lkc], kub = sku[lkr + 1][lkc];
            float kvc = skv[lkr][lkc], kvl = skv[lkr][lkc - 1], kvr = skv[lkr][lkc + 1], kvt = skv[lkr - 1][lkc], kvb = skv[lkr + 1][lkc];
            float uc = u6[c + 1], ul = u6[c], ur = u6[c + 2], ut = uu[c], ub = ud[c];
            float vc = v6[c + 1], vl = v6[c], vr = v6[c + 2], vt = vu[c], vb = vd[c];
            float ADxbu = 0.5f * (bur - bul), ADybu = 0.5f * (bub - but);
            float ADxbv = 0.5f * (bvr - bvl), ADybv = 0.5f * (bvb - bvt);
            float Lbu = bul + bur + but + bub - 4.f * buc;
            float Lbv = bvl + bvr + bvt + bvb - 4.f * bvc;
            float Lku = kul + kur + kut + kub - 4.f * kuc;
            float Lkv = kvl + kvr + kvt + kvb - 4.f * kvc;
            // product term uses ORIGINAL velocities
            float Luku = ul * kul + ur * kur + ut * kut + ub * kub - 4.f * uc * kuc;
            float Lvkv = vl * kvl + vr * kvr + vt * kvt + vb * kvb - 4.f * vc * kvc;
            float kx = 1.5f * (kuc * Lbu + Luku - buc * Lku);
            float ky = 1.5f * (kvc * Lbv + Lvkv - bvc * Lkv);
            float Grapx = 0.5f * (p6[c + 2] - p6[c]) * DT;
            float Grapy = 0.5f * (pd[c] - pu[c]) * DT;
            oun[c] = uc + kx * DT - buc * ADxbu * DT - bvc * ADybu * DT - Grapx - fx[c] * DT;
            ovn[c] = vc + ky * DT - buc * ADxbv * DT - bvc * ADybv * DT - Grapy - fy[c] * DT;
        }
        store4(un, i, j0, oun);
        store4(vn, i, j0, ovn);
    }
}

// ---------------- pressure RHS: b = -div(u_new)/DT ----------------
__global__ __launch_bounds__(256) void k_rhs_v(const float* __restrict__ un, const float* __restrict__ vn,
                                               float* __restrict__ b) {
    const float INVDT = 100.0f;
    int jt = blockIdx.x * blockDim.x + threadIdx.x;
    int i  = blockIdx.y * blockDim.y + threadIdx.y;
    int j0 = jt * 4;
    float u6[6], vu[4], vd[4], ob[4];
    load6z(un, i, j0, u6);
    load4z(vn, i - 1, j0, vu); load4z(vn, i + 1, j0, vd);
#pragma unroll
    for (int c = 0; c < 4; ++c) {
        float adx = 0.5f * (u6[c + 2] - u6[c]);
        float ady = 0.5f * (vd[c] - vu[c]);
        ob[c] = -(adx + ady) * INVDT;
    }
    store4(b, i, j0, ob);
}

// -------- fused residual + restrict to 1024/512/256/128 --------
__global__ __launch_bounds__(256) void k_resrestrict(const float* __restrict__ p, const float* __restrict__ b,
                                                     float* __restrict__ r1024, float* __restrict__ r512,
                                                     float* __restrict__ r256, float* __restrict__ r128) {
    __shared__ float s512[4][64];
    __shared__ float s256[2][32];
    int tx = threadIdx.x, ty = threadIdx.y;
    int jt = blockIdx.x * 64 + tx;   // [0,512)
    int it = blockIdx.y * 4 + ty;    // [0,512)
    int j0 = jt * 4, i0 = it * 4;
    float p6[6][6];
#pragma unroll
    for (int r = 0; r < 6; ++r) load6e(p, i0 - 1 + r, j0, p6[r]);
    float res[4][4];
#pragma unroll
    for (int r = 0; r < 4; ++r) {
        float bb[4];
        load4z(b, i0 + r, j0, bb);
#pragma unroll
        for (int c = 0; c < 4; ++c) {
            float pc = p6[r + 1][c + 1];
            float nb = p6[r][c + 1] + p6[r + 2][c + 1] + p6[r + 1][c] + p6[r + 1][c + 2];
            res[r][c] = nb - 4.f * pc - bb[c];
        }
    }
    float q00 = 0.25f * (res[0][0] + res[0][1] + res[1][0] + res[1][1]);
    float q01 = 0.25f * (res[0][2] + res[0][3] + res[1][2] + res[1][3]);
    float q10 = 0.25f * (res[2][0] + res[2][1] + res[3][0] + res[3][1]);
    float q11 = 0.25f * (res[2][2] + res[2][3] + res[3][2] + res[3][3]);
    int ci = it * 2, cj = jt * 2;
    *reinterpret_cast<float2*>(r1024 + (size_t)ci * 1024 + cj)       = make_float2(q00, q01);
    *reinterpret_cast<float2*>(r1024 + (size_t)(ci + 1) * 1024 + cj) = make_float2(q10, q11);
    float s = 0.25f * (q00 + q01 + q10 + q11);
    r512[(size_t)it * 512 + jt] = s;
    s512[ty][tx] = s;
    __syncthreads();
    int tid = ty * 64 + tx;
    if (tid < 64) {
        int a = tid >> 5, c = tid & 31;
        float m = 0.25f * (s512[2 * a][2 * c] + s512[2 * a][2 * c + 1] + s512[2 * a + 1][2 * c] + s512[2 * a + 1][2 * c + 1]);
        r256[(size_t)(blockIdx.y * 2 + a) * 256 + blockIdx.x * 32 + c] = m;
        s256[a][c] = m;
    }
    __syncthreads();
    if (tid < 16) {
        float m = 0.25f * (s256[0][2 * tid] + s256[0][2 * tid + 1] + s256[1][2 * tid] + s256[1][2 * tid + 1]);
        r128[(size_t)blockIdx.y * 128 + blockIdx.x * 16 + tid] = m;
    }
}

// ---------------- all coarse levels (<=128) in one block ----------------
__global__ __launch_bounds__(1024) void k_small(const float* __restrict__ r128,
                                                float* __restrict__ w128_out,
                                                float* __restrict__ r2_out) {
    __shared__ float sr64[64 * 64];
    __shared__ float sr32[32 * 32];
    __shared__ float sr16[16 * 16];
    __shared__ float sr8[8 * 8];
    __shared__ float sr4[16];
    __shared__ float sr2[4];
    __shared__ float wa[64 * 64];
    __shared__ float wb[64 * 64];
    int t = threadIdx.x;

    for (int idx = t; idx < 64 * 64; idx += 1024) {
        int i = idx >> 6, j = idx & 63;
        const float* s0 = r128 + (2 * i) * 128 + 2 * j;
        sr64[idx] = 0.25f * (s0[0] + s0[1] + s0[128] + s0[129]);
    }
    __syncthreads();
    if (t < 32 * 32) {
        int i = t >> 5, j = t & 31;
        const float* s0 = sr64 + (2 * i) * 64 + 2 * j;
        sr32[t] = 0.25f * (s0[0] + s0[1] + s0[64] + s0[65]);
    }
    __syncthreads();
    if (t < 16 * 16) {
        int i = t >> 4, j = t & 15;
        const float* s0 = sr32 + (2 * i) * 32 + 2 * j;
        sr16[t] = 0.25f * (s0[0] + s0[1] + s0[32] + s0[33]);
    }
    __syncthreads();
    if (t < 64) {
        int i = t >> 3, j = t & 7;
        const float* s0 = sr16 + (2 * i) * 16 + 2 * j;
        sr8[t] = 0.25f * (s0[0] + s0[1] + s0[16] + s0[17]);
    }
    __syncthreads();
    if (t < 16) {
        int i = t >> 2, j = t & 3;
        const float* s0 = sr8 + (2 * i) * 8 + 2 * j;
        sr4[t] = 0.25f * (s0[0] + s0[1] + s0[8] + s0[9]);
    }
    __syncthreads();
    if (t < 4) {
        int i = t >> 1, j = t & 1;
        const float* s0 = sr4 + (2 * i) * 4 + 2 * j;
        sr2[t] = 0.25f * (s0[0] + s0[1] + s0[4] + s0[5]);
        r2_out[t] = sr2[t];
        float ws = -0.25f * sr2[t];
        wa[(2 * i) * 4 + 2 * j] = ws;
        wa[(2 * i) * 4 + 2 * j + 1] = ws;
        wa[(2 * i + 1) * 4 + 2 * j] = ws;
        wa[(2 * i + 1) * 4 + 2 * j + 1] = ws;
    }
    __syncthreads();

    auto step = [&](const float* win, const float* rl, float* wout, int s) {
        for (int idx = t; idx < s * s; idx += 1024) {
            int i = idx / s, j = idx - i * s;
            float up = i > 0 ? win[(i - 1) * s + j] : 0.f;
            float dn = i < s - 1 ? win[(i + 1) * s + j] : 0.f;
            float lf = j > 0 ? win[i * s + j - 1] : 0.f;
            float rt = j < s - 1 ? win[i * s + j + 1] : 0.f;
            float ws = 0.25f * (up + dn + lf + rt - rl[idx]);
            int o = 2 * s;
            wout[(2 * i) * o + 2 * j] = ws;
            wout[(2 * i) * o + 2 * j + 1] = ws;
            wout[(2 * i + 1) * o + 2 * j] = ws;
            wout[(2 * i + 1) * o + 2 * j + 1] = ws;
        }
    };
    step(wa, sr4, wb, 4);
    __syncthreads();
    step(wb, sr8, wa, 8);
    __syncthreads();
    step(wa, sr16, wb, 16);
    __syncthreads();
    step(wb, sr32, wa, 32);
    __syncthreads();
    step(wa, sr64, w128_out, 64);
}

// ---------------- smooth + upsample, one mid level ----------------
__global__ __launch_bounds__(256) void k_prolong(const float* __restrict__ win, const float* __restrict__ rl,
                                                 float* __restrict__ wout, int n) {
    int j = blockIdx.x * blockDim.x + threadIdx.x;
    int i = blockIdx.y * blockDim.y + threadIdx.y;
    float up = i > 0 ? win[(i - 1) * n + j] : 0.f;
    float dn = i < n - 1 ? win[(i + 1) * n + j] : 0.f;
    float lf = j > 0 ? win[i * n + j - 1] : 0.f;
    float rt = j < n - 1 ? win[i * n + j + 1] : 0.f;
    float ws = 0.25f * (up + dn + lf + rt - rl[i * n + j]);
    int o = 2 * n;
    float2 vv = make_float2(ws, ws);
    *reinterpret_cast<float2*>(wout + (2 * i) * o + 2 * j) = vv;
    *reinterpret_cast<float2*>(wout + (2 * i + 1) * o + 2 * j) = vv;
}

// -------- fused: w512 -> smooth -> W1024 -> smooth -> p update (+ optional out_w) --------
template <bool LAST>
__global__ __launch_bounds__(256) void k_pupd2(const float* __restrict__ p, const float* __restrict__ b,
                                               const float* __restrict__ w512, const float* __restrict__ r512,
                                               const float* __restrict__ r1024,
                                               float* __restrict__ pdst, float* __restrict__ wout) {
    __shared__ float sW[6][72];    // W512 tile (zero outside domain)
    __shared__ float sS[4][68];    // smooth(W512, r512)
    __shared__ float ws[4][130];   // smooth(W1024, r1024) at coarse-1024
    const int jb = blockIdx.x * 256;
    const int ib = blockIdx.y * 4;
    const int cr_base = ib / 2 - 1;
    const int cc_base = jb / 2 - 1;
    const int sr_base = (ib / 2 - 2) >> 1;   // arithmetic shift: floor-div-2
    const int sc_base = (jb / 2 - 2) >> 1;
    const int wr_base = sr_base - 1, wc_base = sc_base - 1;
    const int tid = threadIdx.y * 64 + threadIdx.x;

    for (int idx = tid; idx < 6 * 68; idx += 256) {
        int r = idx / 68, c = idx - r * 68;
        int gi = wr_base + r, gj = wc_base + c;
        sW[r][c] = ((unsigned)gi < 512u && (unsigned)gj < 512u) ? w512[(size_t)gi * 512 + gj] : 0.f;
    }
    __syncthreads();
    for (int idx = tid; idx < 4 * 66; idx += 256) {
        int r = idx / 66, c = idx - r * 66;
        int gi = sr_base + r, gj = sc_base + c;
        float val = 0.f;
        if ((unsigned)gi < 512u && (unsigned)gj < 512u) {
            int lr = r + 1, lc = c + 1;   // gi-wr_base, gj-wc_base
            val = 0.25f * (sW[lr - 1][lc] + sW[lr + 1][lc] + sW[lr][lc - 1] + sW[lr][lc + 1]
                           - r512[(size_t)gi * 512 + gj]);
        }
        sS[r][c] = val;
    }
    __syncthreads();
    for (int idx = tid; idx < 4 * 130; idx += 256) {
        int r = idx / 130, c = idx - r * 130;
        int ci = cr_base + r, cj = cc_base + c;
        float val = 0.f;
        if ((unsigned)ci < 1024u && (unsigned)cj < 1024u) {
            float nsum = 0.f;
            {
                int R = ci - 1, C = cj;
                if ((unsigned)R < 1024u) nsum += sS[(R >> 1) - sr_base][(C >> 1) - sc_base];
            }
            {
                int R = ci + 1, C = cj;
                if ((unsigned)R < 1024u) nsum += sS[(R >> 1) - sr_base][(C >> 1) - sc_base];
            }
            {
                int R = ci, C = cj - 1;
                if ((unsigned)C < 1024u) nsum += sS[(R >> 1) - sr_base][(C >> 1) - sc_base];
            }
            {
                int R = ci, C = cj + 1;
                if ((unsigned)C < 1024u) nsum += sS[(R >> 1) - sr_base][(C >> 1) - sc_base];
            }
            val = 0.25f * (nsum - r1024[(size_t)ci * 1024 + cj]);
        }
        ws[r][c] = val;
    }
    __syncthreads();

    const int i  = ib + threadIdx.y;
    const int j0 = jb + threadIdx.x * 4;
    float p6[6], pu[4], pd[4], bb[4], op[4];
    load6e(p, i, j0, p6);
    load4e(p, i - 1, j0, pu);
    load4e(p, i + 1, j0, pd);
    load4z(b, i, j0, bb);

    const int iu = (i - 1) < 0 ? 0 : (i - 1);
    const int id = (i + 1) > NN - 1 ? NN - 1 : (i + 1);
    const int lrC = (i >> 1) - cr_base;
    const int lrU = (iu >> 1) - cr_base;
    const int lrD = (id >> 1) - cr_base;

#pragma unroll
    for (int c = 0; c < 4; ++c) {
        int f = j0 + c;
        int fl = (f - 1) < 0 ? 0 : (f - 1);
        int fr = (f + 1) > NN - 1 ? NN - 1 : (f + 1);
        float pml = p6[c]     - ws[lrC][(fl >> 1) - cc_base];
        float pmr = p6[c + 2] - ws[lrC][(fr >> 1) - cc_base];
        float pmt = pu[c]     - ws[lrU][(f >> 1) - cc_base];
        float pmb = pd[c]     - ws[lrD][(f >> 1) - cc_base];
        op[c] = 0.25f * (pml + pmr + pmt + pmb - bb[c]);
    }
    store4(pdst, i, j0, op);
    if (LAST) {
        float ow[4];
#pragma unroll
        for (int c = 0; c < 4; ++c) ow[c] = ws[lrC][((j0 + c) >> 1) - cc_base];
        store4(wout, i, j0, ow);
    }
}

// ---------------- final projection ----------------
__global__ __launch_bounds__(256) void k_fcorr_v(const float* __restrict__ p,
                                                 float* __restrict__ un, float* __restrict__ vn) {
    const float DT = 0.01f;
    int jt = blockIdx.x * blockDim.x + threadIdx.x;
    int i  = blockIdx.y * blockDim.y + threadIdx.y;
    int j0 = jt * 4;
    float p6[6], pu[4], pd[4];
    load6e(p, i, j0, p6);
    load4e(p, i - 1, j0, pu);
    load4e(p, i + 1, j0, pd);
    float4 uc = *reinterpret_cast<float4*>(un + (size_t)i * NN + j0);
    float4 vc = *reinterpret_cast<float4*>(vn + (size_t)i * NN + j0);
    float ou[4] = {uc.x, uc.y, uc.z, uc.w};
    float ov[4] = {vc.x, vc.y, vc.z, vc.w};
#pragma unroll
    for (int c = 0; c < 4; ++c) {
        ou[c] -= 0.5f * (p6[c + 2] - p6[c]) * DT;
        ov[c] -= 0.5f * (pd[c] - pu[c]) * DT;
    }
    store4(un, i, j0, ou);
    store4(vn, i, j0, ov);
}

extern "C" void kernel_launch(void* const* d_in, const int* in_sizes, int n_in,
                              void* d_out, int out_size, void* d_ws, size_t ws_size,
                              hipStream_t stream) {
    const float* u  = (const float*)d_in[0];
    const float* v  = (const float*)d_in[1];
    const float* p  = (const float*)d_in[2];
    const float* Fx = (const float*)d_in[3];
    const float* Fy = (const float*)d_in[4];
    const float* k1 = (const float*)d_in[5];

    float* out = (float*)d_out;
    float* out_u = out;
    float* out_v = out + (size_t)NN2;
    float* out_p = out + 2 * (size_t)NN2;
    float* out_w = out + 3 * (size_t)NN2;
    float* out_r = out + 4 * (size_t)NN2;

    float* ws = (float*)d_ws;
    float* b  = ws;
    float* pA = ws + (size_t)NN2;
    float* pB = ws + 2 * (size_t)NN2;
    float* r1024 = ws + 3 * (size_t)NN2;
    float* r512  = r1024 + 1024 * 1024;
    float* r256  = r512 + 512 * 512;
    float* r128  = r256 + 256 * 256;
    float* w128  = r128 + 128 * 128;
    float* w256  = w128 + 128 * 128;
    float* w512  = w256 + 256 * 256;

    // b_u/b_v live in not-yet-needed output regions (dead before w/p are produced)
    float* bu = out_w;
    float* bv = out_p;

    dim3 blk(64, 4);
    dim3 g4(8, 512);        // 2048^2, 4 pts/thread in x
    dim3 blkT(16, 16);
    dim3 gT(32, 64);        // 64x32 tiles

    // momentum (pg1 fused into each consumer)
    k_pred_f<<<gT, blkT, 0, stream>>>(u, v, k1, p, bu, bv);
    k_corr_f<<<gT, blkT, 0, stream>>>(u, v, k1, p, bu, bv, Fx, Fy, out_u, out_v);
    k_rhs_v<<<g4, blk, 0, stream>>>(out_u, out_v, b);

    // multigrid F-cycle, 5 iterations
    const float* pcur = p;
    for (int it = 0; it < 5; ++it) {
        k_resrestrict<<<dim3(8, 128), blk, 0, stream>>>(pcur, b, r1024, r512, r256, r128);
        k_small<<<1, 1024, 0, stream>>>(r128, w128, out_r);
        k_prolong<<<dim3(2, 32), blk, 0, stream>>>(w128, r128, w256, 128);
        k_prolong<<<dim3(4, 64), blk, 0, stream>>>(w256, r256, w512, 256);
        if (it < 4) {
            float* pdst = (it & 1) ? pB : pA;
            k_pupd2<false><<<dim3(8, 512), blk, 0, stream>>>(pcur, b, w512, r512, r1024, pdst, nullptr);
            pcur = pdst;
        } else {
            k_pupd2<true><<<dim3(8, 512), blk, 0, stream>>>(pcur, b, w512, r512, r1024, out_p, out_w);
        }
    }

    // final projection with the new pressure
    k_fcorr_v<<<g4, blk, 0, stream>>>(out_p, out_u, out_v);
}